// Round 5
// baseline (4539.593 us; speedup 1.0000x reference)
//
#include <hip/hip_runtime.h>
#include <math.h>

#define H      1024
#define B      128
#define T      256
#define GROUPS 4
#define BPG    64        // blocks per group; block owns 16 hidden dims (64 gate rows)
#define NTHR   512
#define MPG    32        // batches per group
#define DPB    16        // dims per block
#define GRP_SHORTS (MPG * H)   // 32768 shorts = 64 KB per group per parity

#define AS1 __attribute__((address_space(1)))
#define AS3 __attribute__((address_space(3)))

typedef __attribute__((ext_vector_type(8))) short  bf16x8;
typedef __attribute__((ext_vector_type(4))) float  floatx4;
typedef __attribute__((ext_vector_type(4))) int    int4v;

static __device__ __forceinline__ unsigned short bf16_rne(float f) {
    unsigned int u = __float_as_uint(f);
    u += 0x7FFF + ((u >> 16) & 1);
    return (unsigned short)(u >> 16);
}
static __device__ __forceinline__ float bf16_to_f(unsigned short h) {
    return __uint_as_float(((unsigned int)h) << 16);
}
static __device__ __forceinline__ float sigmoidf_(float x) { return 1.0f / (1.0f + __expf(-x)); }

// h element (m, k) -> fragment-major short index (consumer DMA layout):
// chunk c = kt*2 + mt (1024 B), slot = q*16 + (m&15), inner j = k&7.
static __device__ __forceinline__ void store_h_frag(unsigned short* base, int m, int k, float v) {
    const int kt = k >> 5, q = (k >> 3) & 3, j = k & 7;
    const int c  = kt * 2 + (m >> 4);
    base[c * 512 + (q * 16 + (m & 15)) * 8 + j] = bf16_rne(v);
}

static __device__ __forceinline__ void dma16(const void* g, void* l) {
    __builtin_amdgcn_global_load_lds((const AS1 void*)g, (AS3 void*)l, 16, 0, 0);
}
// write-through stores: land at the device coherence point (L3), leave no
// dirty L2 line behind => no buffer_wbl2 ever needed in the loop.
static __device__ __forceinline__ void store16_wt(void* p, int4v v) {
    asm volatile("global_store_dwordx4 %0, %1, off sc0 sc1" :: "v"(p), "v"(v) : "memory");
}
static __device__ __forceinline__ void store4_wt(void* p, float v) {
    asm volatile("global_store_dword %0, %1, off sc0 sc1" :: "v"(p), "v"(v) : "memory");
}

// Flag-array group barrier: block rb's flag at flags[rb*32] (128 B apart).
// Wait: every wave gathers all 64 flags in ONE 64-lane load and reduces with
// __all(); no RMWs, no leader hop. Final ACQUIRE load emits the buffer_inv
// that keeps subsequent DMA reads coherent.
static __device__ __forceinline__ void flag_wait(unsigned int* flags, int lane,
                                                 unsigned int gen) {
    unsigned int* my = flags + lane * 32;
    for (;;) {
        unsigned int v = __hip_atomic_load(my, __ATOMIC_RELAXED, __HIP_MEMORY_SCOPE_AGENT);
        if (__all((int)(v >= gen))) break;
    }
    (void)__hip_atomic_load(my, __ATOMIC_ACQUIRE, __HIP_MEMORY_SCOPE_AGENT);
}

// Persistent LSTM decoder. 4 groups x 64 blocks; group g owns batches
// [32g, 32g+32). Block rb owns hidden dims [16rb, 16rb+16) => 64 gate rows.
// W' = W_hh + W_ih[:,0] (x) W_lin in registers as split hi/lo bf16 B-frags.
// h travels bf16 fragment-major via write-through stores -> L3 -> DMA to LDS.
__global__ __launch_bounds__(NTHR, 2) void decoder_kernel(
    const float* __restrict__ hidden0, const float* __restrict__ cell0,
    const float* __restrict__ Wih,     const float* __restrict__ Whh,
    const float* __restrict__ bih,     const float* __restrict__ bhh,
    const float* __restrict__ Wlin,    const float* __restrict__ blin,
    float* __restrict__ out,           float* __restrict__ ws)
{
    __shared__ unsigned short planes[64 * 512];      // 64 KB staged h (bf16 frags)
    __shared__ float Dlds[4][2][32][18];             // 18 KB gate partials (pad 18)
    __shared__ float s0_lds[MPG];

    const int blk  = blockIdx.x;
    const int g    = blk >> 6;
    const int rb   = blk & 63;
    const int tid  = threadIdx.x;
    const int lane = tid & 63;
    const int wave = tid >> 6;          // 8 waves: (gate, kh)
    const int gate = wave & 3;
    const int kh   = wave >> 2;
    const int l15  = lane & 15;
    const int q    = lane >> 4;

    // ws layout: flags (4 groups x 64 x 128 B = 32 KB) | hbuf 512 KB | pbuf 64 KB
    unsigned int*   flags = (unsigned int*)ws + g * 2048;
    unsigned short* hbuf  = (unsigned short*)((char*)ws + 32768);
    float*          pbuf  = (float*)((char*)ws + 32768 + 2 * GROUPS * GRP_SHORTS * 2);

    // ---- W' B-fragments in registers (split hi/lo bf16) ----
    const int row = gate * H + rb * DPB + l15;
    bf16x8 w_hi[16], w_lo[16];
    {
        const float* wrow  = Whh + (size_t)row * H;
        const float  wih0r = Wih[row * 2];
        #pragma unroll
        for (int kt = 0; kt < 16; ++kt) {
            const int k0 = kh * 512 + kt * 32 + q * 8;
            #pragma unroll
            for (int j = 0; j < 8; ++j) {
                float w = wrow[k0 + j] + wih0r * Wlin[k0 + j];
                unsigned short hs = bf16_rne(w);
                float lo = w - bf16_to_f(hs);
                w_hi[kt][j] = (short)hs;
                w_lo[kt][j] = (short)bf16_rne(lo);
            }
        }
    }

    // ---- pointwise-thread constants: thread (pm, pj), lane = (pm&3)*16+pj ----
    const int pm    = tid >> 4;               // batch in group 0..31
    const int pj    = tid & 15;               // dim within block 0..15
    const int bglob = g * MPG + pm;
    const int kdim  = rb * DPB + pj;
    const float bl  = blin[0];
    float bias_p[4], bias0_p[4], wih0_p[4];
    #pragma unroll
    for (int gt = 0; gt < 4; ++gt) {
        int r2 = gt * H + kdim;
        float b0 = bih[r2] + bhh[r2];
        float w0 = Wih[r2 * 2];
        bias0_p[gt] = b0;
        wih0_p[gt]  = w0;
        bias_p[gt]  = b0 + Wih[r2 * 2 + 1] + w0 * bl;   // folded bias (t>=1)
    }
    float cstate = cell0[(size_t)bglob * H + kdim];
    const float wlin_p = Wlin[kdim];

    // h-frag store address pieces for the packed 16 B store (lanes pj%8==0)
    const int qq  = (rb & 1) * 2 + (pj >> 3);
    const int cc  = (rb >> 1) * 2 + (pm >> 4);
    const int hoff = cc * 512 + (qq * 16 + (pm & 15)) * 8;

    // ---- s0[m] = Wlin . h0[m]  (t=0 rank-1 correction) ----
    {
        const float* hp = hidden0 + (size_t)bglob * H + pj * 64;
        const float* wp = Wlin + pj * 64;
        float s = 0.f;
        #pragma unroll 4
        for (int kk = 0; kk < 64; kk += 4) {
            float4 hv = *(const float4*)(hp + kk);
            float4 wv = *(const float4*)(wp + kk);
            s += hv.x * wv.x + hv.y * wv.y + hv.z * wv.z + hv.w * wv.w;
        }
        s += __shfl_xor(s, 1); s += __shfl_xor(s, 2);
        s += __shfl_xor(s, 4); s += __shfl_xor(s, 8);
        if (pj == 0) s0_lds[pm] = s;
    }

    // ---- preamble: h0 slice into hbuf parity 0; one-time fence; barrier ----
    {
        unsigned short* dst = hbuf + (size_t)(0 * GROUPS + g) * GRP_SHORTS;
        store_h_frag(dst, pm, kdim, hidden0[(size_t)bglob * H + kdim]);
    }
    __threadfence();   // one-time wbl2: flush preamble plain stores to L3
    __syncthreads();
    if (tid == 0)
        __hip_atomic_store(&flags[rb * 32], 1u, __ATOMIC_RELAXED, __HIP_MEMORY_SCOPE_AGENT);
    flag_wait(flags, lane, 1u);

    for (int t = 0; t < T; ++t) {
        // ---- phase A: DMA h_t -> LDS; wave1 reduces step t-1 output head ----
        const unsigned short* hsrc = hbuf + (size_t)((t & 1) * GROUPS + g) * GRP_SHORTS;
        #pragma unroll
        for (int i = 0; i < 8; ++i) {
            const int c = wave * 8 + i;
            dma16(hsrc + c * 512 + lane * 8, planes + c * 512);
        }
        if (wave == 1 && rb < MPG && t > 0) {
            // batch m = rb: sum 64 block-partials written at step t-1
            float v = pbuf[((size_t)(((t - 1) & 1) * GROUPS + g) * BPG + lane) * MPG + rb];
            v += __shfl_xor(v, 1);  v += __shfl_xor(v, 2);  v += __shfl_xor(v, 4);
            v += __shfl_xor(v, 8);  v += __shfl_xor(v, 16); v += __shfl_xor(v, 32);
            if (lane == 0) out[(size_t)(g * MPG + rb) * T + (t - 1)] = v + bl;
        }
        __syncthreads();   // per-wave vmcnt drain => DMA complete

        // ---- phase B: MFMA D[m][n] += h[m][k] W'[n][k], K-half kh ----
        floatx4 acc0 = {0.f, 0.f, 0.f, 0.f};
        floatx4 acc1 = {0.f, 0.f, 0.f, 0.f};
        #pragma unroll
        for (int kt16 = 0; kt16 < 16; ++kt16) {
            const int kt = kh * 16 + kt16;
            bf16x8 a0 = *(const bf16x8*)(planes + (kt * 2 + 0) * 512 + lane * 8);
            bf16x8 a1 = *(const bf16x8*)(planes + (kt * 2 + 1) * 512 + lane * 8);
            acc0 = __builtin_amdgcn_mfma_f32_16x16x32_bf16(a0, w_hi[kt16], acc0, 0, 0, 0);
            acc0 = __builtin_amdgcn_mfma_f32_16x16x32_bf16(a0, w_lo[kt16], acc0, 0, 0, 0);
            acc1 = __builtin_amdgcn_mfma_f32_16x16x32_bf16(a1, w_hi[kt16], acc1, 0, 0, 0);
            acc1 = __builtin_amdgcn_mfma_f32_16x16x32_bf16(a1, w_lo[kt16], acc1, 0, 0, 0);
        }
        #pragma unroll
        for (int r = 0; r < 4; ++r) {       // C/D: col=lane&15, row=q*4+r
            Dlds[gate][kh][q * 4 + r][l15]      = acc0[r];
            Dlds[gate][kh][16 + q * 4 + r][l15] = acc1[r];
        }
        __syncthreads();

        // ---- phase C: pointwise + cross-lane pack + write-through stores ----
        {
            float gi = Dlds[0][0][pm][pj] + Dlds[0][1][pm][pj];
            float gf = Dlds[1][0][pm][pj] + Dlds[1][1][pm][pj];
            float gg = Dlds[2][0][pm][pj] + Dlds[2][1][pm][pj];
            float go = Dlds[3][0][pm][pj] + Dlds[3][1][pm][pj];
            if (t == 0) {
                float s0 = s0_lds[pm];
                gi += bias0_p[0] - wih0_p[0] * s0;
                gf += bias0_p[1] - wih0_p[1] * s0;
                gg += bias0_p[2] - wih0_p[2] * s0;
                go += bias0_p[3] - wih0_p[3] * s0;
            } else {
                gi += bias_p[0]; gf += bias_p[1];
                gg += bias_p[2]; go += bias_p[3];
            }
            float ig  = sigmoidf_(gi);
            float fg  = sigmoidf_(gf);
            float gt_ = tanhf(gg);
            float og  = sigmoidf_(go);
            cstate = fg * cstate + ig * gt_;
            float hnew = og * tanhf(cstate);

            // pack 8 lanes' bf16 into one lane's 16 B, store write-through
            unsigned int hv = (unsigned int)bf16_rne(hnew);
            unsigned int p1 = __shfl_xor(hv, 1);
            unsigned int d  = (pj & 1) ? ((hv << 16) | p1) : ((p1 << 16) | hv);
            const int base  = (lane & 48) | (pj & 8);   // run-start lane
            unsigned int dw0 = __shfl(d, base);
            unsigned int dw1 = __shfl(d, base + 2);
            unsigned int dw2 = __shfl(d, base + 4);
            unsigned int dw3 = __shfl(d, base + 6);
            if ((pj & 7) == 0) {
                unsigned short* hdst =
                    hbuf + (size_t)(((t + 1) & 1) * GROUPS + g) * GRP_SHORTS + hoff;
                int4v v4 = { (int)dw0, (int)dw1, (int)dw2, (int)dw3 };
                store16_wt(hdst, v4);
            }
            // out-head partial: reduce over this block's 16 dims
            float po = wlin_p * hnew;
            po += __shfl_xor(po, 1); po += __shfl_xor(po, 2);
            po += __shfl_xor(po, 4); po += __shfl_xor(po, 8);
            if (pj == 0)
                store4_wt(pbuf + ((size_t)((t & 1) * GROUPS + g) * BPG + rb) * MPG + pm, po);
        }
        __syncthreads();   // per-wave vmcnt(0): all wt stores at L3 before arrive

        // ---- phase D: flag barrier (arrive + all-wave gather-poll) ----
        if (tid == 0)
            __hip_atomic_store(&flags[rb * 32], (unsigned int)(t + 2),
                               __ATOMIC_RELAXED, __HIP_MEMORY_SCOPE_AGENT);
        flag_wait(flags, lane, (unsigned int)(t + 2));
    }

    // ---- epilogue: output column t = T-1 ----
    if (wave == 1 && rb < MPG) {
        float v = pbuf[((size_t)(((T - 1) & 1) * GROUPS + g) * BPG + lane) * MPG + rb];
        v += __shfl_xor(v, 1);  v += __shfl_xor(v, 2);  v += __shfl_xor(v, 4);
        v += __shfl_xor(v, 8);  v += __shfl_xor(v, 16); v += __shfl_xor(v, 32);
        if (lane == 0) out[(size_t)(g * MPG + rb) * T + (T - 1)] = v + bl;
    }
}

extern "C" void kernel_launch(void* const* d_in, const int* in_sizes, int n_in,
                              void* d_out, int out_size, void* d_ws, size_t ws_size,
                              hipStream_t stream) {
    const float* hidden0 = (const float*)d_in[0];
    const float* cell0   = (const float*)d_in[1];
    const float* Wih     = (const float*)d_in[2];
    const float* Whh     = (const float*)d_in[3];
    const float* bih     = (const float*)d_in[4];
    const float* bhh     = (const float*)d_in[5];
    const float* Wlin    = (const float*)d_in[6];
    const float* blin    = (const float*)d_in[7];
    float* out = (float*)d_out;
    float* ws  = (float*)d_ws;

    // zero the barrier flags
    hipMemsetAsync(d_ws, 0, 32768, stream);

    void* args[] = { &hidden0, &cell0, &Wih, &Whh, &bih, &bhh, &Wlin, &blin,
                     &out, &ws };
    hipLaunchCooperativeKernel((const void*)decoder_kernel,
                               dim3(GROUPS * BPG), dim3(NTHR), args, 0, stream);
}

// Round 7
// 1724.320 us; speedup vs baseline: 2.6327x; 2.6327x over previous
//
#include <hip/hip_runtime.h>
#include <math.h>

#define H      1024
#define B      128
#define T      256
#define GROUPS 4
#define BPG    64        // blocks per group; block owns 16 hidden dims (64 gate rows)
#define NTHR   512
#define MPG    32        // batches per group
#define DPB    16        // dims per block
#define GRP_SHORTS (MPG * H)   // 32768 shorts = 64 KB per group per parity

#define AS1 __attribute__((address_space(1)))
#define AS3 __attribute__((address_space(3)))

typedef __attribute__((ext_vector_type(8))) short  bf16x8;
typedef __attribute__((ext_vector_type(4))) float  floatx4;
typedef __attribute__((ext_vector_type(4))) int    int4v;

static __device__ __forceinline__ unsigned short bf16_rne(float f) {
    unsigned int u = __float_as_uint(f);
    u += 0x7FFF + ((u >> 16) & 1);
    return (unsigned short)(u >> 16);
}
static __device__ __forceinline__ float bf16_to_f(unsigned short h) {
    return __uint_as_float(((unsigned int)h) << 16);
}
static __device__ __forceinline__ float sigmoidf_(float x) { return 1.0f / (1.0f + __expf(-x)); }

// h element (m, k) -> fragment-major short index (consumer DMA layout):
// chunk c = kt*2 + mt (1024 B), slot = q*16 + (m&15), inner j = k&7.
static __device__ __forceinline__ void store_h_frag(unsigned short* base, int m, int k, float v) {
    const int kt = k >> 5, q = (k >> 3) & 3, j = k & 7;
    const int c  = kt * 2 + (m >> 4);
    base[c * 512 + (q * 16 + (m & 15)) * 8 + j] = bf16_rne(v);
}

static __device__ __forceinline__ void dma16(const void* g, void* l) {
    __builtin_amdgcn_global_load_lds((const AS1 void*)g, (AS3 void*)l, 16, 0, 0);
}
// write-through stores: land at the device coherence point, leave no dirty L2
// line behind => no buffer_wbl2 needed anywhere in the loop (R4's key win).
static __device__ __forceinline__ void store16_wt(void* p, int4v v) {
    asm volatile("global_store_dwordx4 %0, %1, off sc0 sc1" :: "v"(p), "v"(v) : "memory");
}
static __device__ __forceinline__ void store4_wt(void* p, float v) {
    asm volatile("global_store_dword %0, %1, off sc0 sc1" :: "v"(p), "v"(v) : "memory");
}

// Persistent LSTM decoder. 4 groups x 64 blocks (256 blocks, 1/CU — the
// R4-proven launch config). Group g owns batches [32g,32g+32); block rb owns
// hidden dims [16rb,16rb+16) => 64 gate rows. W' = W_hh + W_ih[:,0](x)W_lin in
// registers as split hi/lo bf16 B-frags. h travels bf16 fragment-major via
// write-through stores -> L3 -> global_load_lds DMA.
//
// Barrier: 64 packed flags (256 B = 4 lines per group). Arrive = one relaxed
// dword store by tid0 (zero RMWs). Wait = wave0 only: one 64-lane gather of
// all flags per poll iteration + __all reduce; one ACQUIRE load at the end
// supplies the per-step buffer_inv that keeps the DMA reads coherent.
__global__ __launch_bounds__(NTHR, 2) void decoder_kernel(
    const float* __restrict__ hidden0, const float* __restrict__ cell0,
    const float* __restrict__ Wih,     const float* __restrict__ Whh,
    const float* __restrict__ bih,     const float* __restrict__ bhh,
    const float* __restrict__ Wlin,    const float* __restrict__ blin,
    float* __restrict__ out,           float* __restrict__ ws)
{
    __shared__ unsigned short planes[64 * 512];      // 64 KB staged h (bf16 frags)
    __shared__ float Dlds[4][2][MPG][18];            // 18 KB gate partials (pad 18)
    __shared__ float s0_lds[MPG];

    const int blk  = blockIdx.x;
    const int g    = blk >> 6;
    const int rb   = blk & 63;
    const int tid  = threadIdx.x;
    const int lane = tid & 63;
    const int wave = tid >> 6;          // 8 waves: (gate, kh)
    const int gate = wave & 3;
    const int kh   = wave >> 2;
    const int l15  = lane & 15;
    const int q    = lane >> 4;

    // ws: flags 4 groups x 64 packed uints (256 B each) | hbuf 512 KB | pbuf 64 KB
    unsigned int*   flags = (unsigned int*)ws + g * 64;
    unsigned short* hbuf  = (unsigned short*)((char*)ws + 4096);   // [2][G][GRP_SHORTS]
    float*          pbuf  = (float*)((char*)ws + 4096 + 2 * GROUPS * GRP_SHORTS * 2); // [2][G][BPG][MPG]

    // ---- W' B-fragments in registers (split hi/lo bf16) ----
    const int row = gate * H + rb * DPB + l15;
    bf16x8 w_hi[16], w_lo[16];
    {
        const float* wrow  = Whh + (size_t)row * H;
        const float  wih0r = Wih[row * 2];
        #pragma unroll
        for (int kt = 0; kt < 16; ++kt) {
            const int k0 = kh * 512 + kt * 32 + q * 8;
            #pragma unroll
            for (int j = 0; j < 8; ++j) {
                float w = wrow[k0 + j] + wih0r * Wlin[k0 + j];
                unsigned short hs = bf16_rne(w);
                float lo = w - bf16_to_f(hs);
                w_hi[kt][j] = (short)hs;
                w_lo[kt][j] = (short)bf16_rne(lo);
            }
        }
    }

    // ---- pointwise-thread constants: thread (pm, pj), lane = (pm&3)*16+pj ----
    const int pm    = tid >> 4;               // batch in group 0..31
    const int pj    = tid & 15;               // dim within block 0..15
    const int bglob = g * MPG + pm;
    const int kdim  = rb * DPB + pj;
    const float bl  = blin[0];
    float bias_p[4], bias0_p[4], wih0_p[4];
    #pragma unroll
    for (int gt = 0; gt < 4; ++gt) {
        int r2 = gt * H + kdim;
        float b0 = bih[r2] + bhh[r2];
        float w0 = Wih[r2 * 2];
        bias0_p[gt] = b0;
        wih0_p[gt]  = w0;
        bias_p[gt]  = b0 + Wih[r2 * 2 + 1] + w0 * bl;   // folded bias (t>=1)
    }
    float cstate = cell0[(size_t)bglob * H + kdim];
    const float wlin_p = Wlin[kdim];

    // h-frag store address pieces for the packed 16 B store (lanes pj%8==0)
    const int qq  = (rb & 1) * 2 + (pj >> 3);
    const int cc  = (rb >> 1) * 2 + (pm >> 4);
    const int hoff = cc * 512 + (qq * 16 + (pm & 15)) * 8;

    // ---- s0[m] = Wlin . h0[m]  (t=0 rank-1 correction) ----
    {
        const float* hp = hidden0 + (size_t)bglob * H + pj * 64;
        const float* wp = Wlin + pj * 64;
        float s = 0.f;
        #pragma unroll 4
        for (int kk = 0; kk < 64; kk += 4) {
            float4 hv = *(const float4*)(hp + kk);
            float4 wv = *(const float4*)(wp + kk);
            s += hv.x * wv.x + hv.y * wv.y + hv.z * wv.z + hv.w * wv.w;
        }
        s += __shfl_xor(s, 1); s += __shfl_xor(s, 2);
        s += __shfl_xor(s, 4); s += __shfl_xor(s, 8);
        if (pj == 0) s0_lds[pm] = s;
    }

    // ---- preamble: h0 slice into hbuf parity 0; one-time fence; barrier ----
    {
        unsigned short* dst = hbuf + (size_t)(0 * GROUPS + g) * GRP_SHORTS;
        store_h_frag(dst, pm, kdim, hidden0[(size_t)bglob * H + kdim]);
    }
    __threadfence();   // one-time wbl2: flush preamble plain stores to coherence point
    __syncthreads();
    if (tid == 0)
        __hip_atomic_store(&flags[rb], 1u, __ATOMIC_RELAXED, __HIP_MEMORY_SCOPE_AGENT);
    if (wave == 0) {
        for (;;) {
            unsigned int v = __hip_atomic_load(&flags[lane], __ATOMIC_RELAXED,
                                               __HIP_MEMORY_SCOPE_AGENT);
            if (__all((int)(v >= 1u))) break;
        }
        (void)__hip_atomic_load(&flags[lane], __ATOMIC_ACQUIRE, __HIP_MEMORY_SCOPE_AGENT);
    }
    __syncthreads();

    for (int t = 0; t < T; ++t) {
        // ---- phase A: DMA h_t -> LDS (8 KB/wave); wave1 reduces t-1 head ----
        const unsigned short* hsrc = hbuf + (size_t)((t & 1) * GROUPS + g) * GRP_SHORTS;
        #pragma unroll
        for (int i = 0; i < 8; ++i) {
            const int c = wave * 8 + i;
            dma16(hsrc + c * 512 + lane * 8, planes + c * 512);
        }
        if (wave == 1 && rb < MPG && t > 0) {
            // batch m = rb: sum 64 block-partials written at step t-1
            float v = pbuf[((size_t)(((t - 1) & 1) * GROUPS + g) * BPG + lane) * MPG + rb];
            v += __shfl_xor(v, 1);  v += __shfl_xor(v, 2);  v += __shfl_xor(v, 4);
            v += __shfl_xor(v, 8);  v += __shfl_xor(v, 16); v += __shfl_xor(v, 32);
            if (lane == 0) out[(size_t)(g * MPG + rb) * T + (t - 1)] = v + bl;
        }
        __syncthreads();   // per-wave vmcnt drain => DMA complete

        // ---- phase B: MFMA D[m][n] += h[m][k] W'[n][k], K-half kh ----
        floatx4 acc0 = {0.f, 0.f, 0.f, 0.f};
        floatx4 acc1 = {0.f, 0.f, 0.f, 0.f};
        #pragma unroll
        for (int kt16 = 0; kt16 < 16; ++kt16) {
            const int kt = kh * 16 + kt16;
            bf16x8 a0 = *(const bf16x8*)(planes + (kt * 2 + 0) * 512 + lane * 8);
            bf16x8 a1 = *(const bf16x8*)(planes + (kt * 2 + 1) * 512 + lane * 8);
            acc0 = __builtin_amdgcn_mfma_f32_16x16x32_bf16(a0, w_hi[kt16], acc0, 0, 0, 0);
            acc0 = __builtin_amdgcn_mfma_f32_16x16x32_bf16(a0, w_lo[kt16], acc0, 0, 0, 0);
            acc1 = __builtin_amdgcn_mfma_f32_16x16x32_bf16(a1, w_hi[kt16], acc1, 0, 0, 0);
            acc1 = __builtin_amdgcn_mfma_f32_16x16x32_bf16(a1, w_lo[kt16], acc1, 0, 0, 0);
        }
        #pragma unroll
        for (int r = 0; r < 4; ++r) {       // C/D: col=lane&15, row=q*4+r
            Dlds[gate][kh][q * 4 + r][l15]      = acc0[r];
            Dlds[gate][kh][16 + q * 4 + r][l15] = acc1[r];
        }
        __syncthreads();

        // ---- phase C: pointwise + cross-lane pack + write-through stores ----
        {
            float gi = Dlds[0][0][pm][pj] + Dlds[0][1][pm][pj];
            float gf = Dlds[1][0][pm][pj] + Dlds[1][1][pm][pj];
            float gg = Dlds[2][0][pm][pj] + Dlds[2][1][pm][pj];
            float go = Dlds[3][0][pm][pj] + Dlds[3][1][pm][pj];
            if (t == 0) {
                float s0 = s0_lds[pm];
                gi += bias0_p[0] - wih0_p[0] * s0;
                gf += bias0_p[1] - wih0_p[1] * s0;
                gg += bias0_p[2] - wih0_p[2] * s0;
                go += bias0_p[3] - wih0_p[3] * s0;
            } else {
                gi += bias_p[0]; gf += bias_p[1];
                gg += bias_p[2]; go += bias_p[3];
            }
            float ig  = sigmoidf_(gi);
            float fg  = sigmoidf_(gf);
            float gt_ = tanhf(gg);
            float og  = sigmoidf_(go);
            cstate = fg * cstate + ig * gt_;
            float hnew = og * tanhf(cstate);

            // pack 8 lanes' bf16 into one lane's 16 B, store write-through
            unsigned int hv = (unsigned int)bf16_rne(hnew);
            unsigned int p1 = __shfl_xor(hv, 1);
            unsigned int d  = (pj & 1) ? ((hv << 16) | p1) : ((p1 << 16) | hv);
            const int base  = (lane & 48) | (pj & 8);   // run-start lane
            unsigned int dw0 = __shfl(d, base);
            unsigned int dw1 = __shfl(d, base + 2);
            unsigned int dw2 = __shfl(d, base + 4);
            unsigned int dw3 = __shfl(d, base + 6);
            if ((pj & 7) == 0) {
                unsigned short* hdst =
                    hbuf + (size_t)(((t + 1) & 1) * GROUPS + g) * GRP_SHORTS + hoff;
                int4v v4 = { (int)dw0, (int)dw1, (int)dw2, (int)dw3 };
                store16_wt(hdst, v4);
            }
            // out-head partial: reduce over this block's 16 dims
            float po = wlin_p * hnew;
            po += __shfl_xor(po, 1); po += __shfl_xor(po, 2);
            po += __shfl_xor(po, 4); po += __shfl_xor(po, 8);
            if (pj == 0)
                store4_wt(pbuf + ((size_t)((t & 1) * GROUPS + g) * BPG + rb) * MPG + pm, po);
        }
        __syncthreads();   // per-wave vmcnt(0): ALL waves' wt stores at L3 before arrive

        // ---- phase D: arrive (tid0 store) + wave0 packed-flag poll + acquire ----
        {
            const unsigned int gen = (unsigned int)(t + 2);
            if (tid == 0)
                __hip_atomic_store(&flags[rb], gen, __ATOMIC_RELAXED, __HIP_MEMORY_SCOPE_AGENT);
            if (wave == 0) {
                for (;;) {
                    unsigned int v = __hip_atomic_load(&flags[lane], __ATOMIC_RELAXED,
                                                       __HIP_MEMORY_SCOPE_AGENT);
                    if (__all((int)(v >= gen))) break;
                }
                (void)__hip_atomic_load(&flags[lane], __ATOMIC_ACQUIRE,
                                        __HIP_MEMORY_SCOPE_AGENT);  // buffer_inv
            }
            __syncthreads();   // release whole block into step t+1
        }
    }

    // ---- epilogue: output column t = T-1 ----
    if (wave == 1 && rb < MPG) {
        float v = pbuf[((size_t)(((T - 1) & 1) * GROUPS + g) * BPG + lane) * MPG + rb];
        v += __shfl_xor(v, 1);  v += __shfl_xor(v, 2);  v += __shfl_xor(v, 4);
        v += __shfl_xor(v, 8);  v += __shfl_xor(v, 16); v += __shfl_xor(v, 32);
        if (lane == 0) out[(size_t)(g * MPG + rb) * T + (T - 1)] = v + bl;
    }
}

extern "C" void kernel_launch(void* const* d_in, const int* in_sizes, int n_in,
                              void* d_out, int out_size, void* d_ws, size_t ws_size,
                              hipStream_t stream) {
    const float* hidden0 = (const float*)d_in[0];
    const float* cell0   = (const float*)d_in[1];
    const float* Wih     = (const float*)d_in[2];
    const float* Whh     = (const float*)d_in[3];
    const float* bih     = (const float*)d_in[4];
    const float* bhh     = (const float*)d_in[5];
    const float* Wlin    = (const float*)d_in[6];
    const float* blin    = (const float*)d_in[7];
    float* out = (float*)d_out;
    float* ws  = (float*)d_ws;

    // zero the barrier flags
    hipMemsetAsync(d_ws, 0, 4096, stream);

    void* args[] = { &hidden0, &cell0, &Wih, &Whh, &bih, &bhh, &Wlin, &blin,
                     &out, &ws };
    hipLaunchCooperativeKernel((const void*)decoder_kernel,
                               dim3(GROUPS * BPG), dim3(NTHR), args, 0, stream);
}

// Round 10
// 1473.375 us; speedup vs baseline: 3.0811x; 1.1703x over previous
//
#include <hip/hip_runtime.h>
#include <math.h>

#define H      1024
#define B      128
#define T      256
#define GROUPS 8        // 8 groups x 32 blocks = 256 blocks (1/CU, R7-proven density)
#define BPG    32       // blocks per group; block owns 32 dims = 128 gate rows
#define NTHR   512
#define MPG    16       // batches per group
#define DPB    32       // dims per block
#define GRP_SHORTS (MPG * H)   // 16384 shorts = 32 KB per group per parity (h hi-plane)

#define AS1 __attribute__((address_space(1)))
#define AS3 __attribute__((address_space(3)))

typedef __attribute__((ext_vector_type(8))) short  bf16x8;
typedef __attribute__((ext_vector_type(4))) float  floatx4;
typedef __attribute__((ext_vector_type(4))) int    int4v;

static __device__ __forceinline__ unsigned short bf16_rne(float f) {
    unsigned int u = __float_as_uint(f);
    u += 0x7FFF + ((u >> 16) & 1);
    return (unsigned short)(u >> 16);
}
static __device__ __forceinline__ float sigmoidf_(float x) { return 1.0f / (1.0f + __expf(-x)); }

// async global->LDS DMA (R7-proven: aux=0)
static __device__ __forceinline__ void dma16(const void* g, void* l) {
    __builtin_amdgcn_global_load_lds((const AS1 void*)g, (AS3 void*)l, 16, 0, 0);
}
// write-through stores: land at the device coherence point, leave no dirty L2
// line behind => no buffer_wbl2 needed anywhere in the loop (R4's key win).
static __device__ __forceinline__ void store16_wt(void* p, int4v v) {
    asm volatile("global_store_dwordx4 %0, %1, off sc0 sc1" :: "v"(p), "v"(v) : "memory");
}
static __device__ __forceinline__ void store4_wt(void* p, float v) {
    asm volatile("global_store_dword %0, %1, off sc0 sc1" :: "v"(p), "v"(v) : "memory");
}

// Persistent LSTM decoder. 8 groups x 32 blocks. Group g owns batches
// [16g,16g+16); block rb owns dims [32rb,32rb+32) => 128 gate rows (8 n-tiles).
// W' = W_hh + W_ih[:,0](x)W_lin, hi-bf16 only, in registers (32 frags = 128
// VGPR). h travels as a single bf16 plane, fragment-major (chunk kt = block
// rb's own 32 dims => producer writes ONE contiguous 1 KB chunk), via
// sc0 sc1 write-through stores -> L3 -> global_load_lds DMA (32 KB/block).
// Barrier: R7-proven packed-flag protocol (tid0 relaxed arrive, wave0 gather
// poll + one ACQUIRE load per step for the buffer_inv).
__global__ __launch_bounds__(NTHR, 2) void decoder_kernel(
    const float* __restrict__ hidden0, const float* __restrict__ cell0,
    const float* __restrict__ Wih,     const float* __restrict__ Whh,
    const float* __restrict__ bih,     const float* __restrict__ bhh,
    const float* __restrict__ Wlin,    const float* __restrict__ blin,
    float* __restrict__ out,           float* __restrict__ ws)
{
    __shared__ unsigned short planes[32 * 512];   // 32 KB staged h (32 chunks of 1 KB)
    __shared__ float Dlds[4][8][MPG][18];         // 36.9 KB: [kh][ntile][m][n+pad]
    __shared__ float s0_lds[MPG];

    const int blk  = blockIdx.x;
    const int g    = blk >> 5;          // group 0..7
    const int rb   = blk & 31;          // block in group 0..31
    const int tid  = threadIdx.x;
    const int lane = tid & 63;
    const int wave = tid >> 6;          // 8 waves: (kh in 4, nh in 2)
    const int kh   = wave & 3;          // K quarter
    const int nh   = wave >> 2;         // n-tile half (4 tiles each)
    const int l15  = lane & 15;
    const int q    = lane >> 4;

    // ws: flags 8 groups x 64 uints (256 B apart) | hbuf 512 KB | pbuf 32 KB
    unsigned int*   flags = (unsigned int*)ws + g * 64;            // 32 used
    unsigned short* hbuf  = (unsigned short*)((char*)ws + 4096);   // [2][G][GRP_SHORTS]
    float*          pbuf  = (float*)((char*)ws + 4096 + 2 * GROUPS * GRP_SHORTS * 2); // [2][G][MPG][BPG]

    // ---- W' hi-bf16 B-fragments in registers: 4 n-tiles x K/4 = 32 frags ----
    bf16x8 w_hi[4][8];
    #pragma unroll
    for (int ntl = 0; ntl < 4; ++ntl) {
        const int nt   = nh * 4 + ntl;          // 0..7; row r = gate*32+d, nt = r>>4
        const int gate = nt >> 1;
        const int row  = gate * H + rb * DPB + (nt & 1) * 16 + l15;
        const float* wrow  = Whh + (size_t)row * H;
        const float  wih0r = Wih[row * 2];
        #pragma unroll
        for (int kt = 0; kt < 8; ++kt) {
            const int k0 = kh * 256 + kt * 32 + q * 8;
            #pragma unroll
            for (int j = 0; j < 8; ++j) {
                float w = wrow[k0 + j] + wih0r * Wlin[k0 + j];
                w_hi[ntl][kt][j] = (short)bf16_rne(w);
            }
        }
    }

    // ---- pointwise-thread constants: thread (pm, pj); lane = (pm&1)*32+pj ----
    const int pm    = tid >> 5;               // batch in group 0..15
    const int pj    = tid & 31;               // dim within block 0..31
    const int bglob = g * MPG + pm;
    const int kdim  = rb * DPB + pj;
    const float bl  = blin[0];
    float bias_p[4], bias0_p[4], wih0_p[4];
    #pragma unroll
    for (int gt = 0; gt < 4; ++gt) {
        int r2 = gt * H + kdim;
        float b0 = bih[r2] + bhh[r2];
        float w0 = Wih[r2 * 2];
        bias0_p[gt] = b0;
        wih0_p[gt]  = w0;
        bias_p[gt]  = b0 + Wih[r2 * 2 + 1] + w0 * bl;   // folded bias (t>=1)
    }
    float cstate = cell0[(size_t)bglob * H + kdim];
    const float wlin_p = Wlin[kdim];

    // h-frag store offset for the packed 16 B store (lanes with pj%8==0):
    // chunk rb, short idx = rb*512 + (pj>>3)*128 + pm*8
    const int hoff = rb * 512 + (pj >> 3) * 128 + pm * 8;

    // ---- s0[m] = Wlin . h0[m]  (t=0 rank-1 correction) ----
    {
        const float* hp = hidden0 + (size_t)bglob * H + pj * 32;
        const float* wp = Wlin + pj * 32;
        float s = 0.f;
        #pragma unroll 4
        for (int kk = 0; kk < 32; kk += 4) {
            float4 hv = *(const float4*)(hp + kk);
            float4 wv = *(const float4*)(wp + kk);
            s += hv.x * wv.x + hv.y * wv.y + hv.z * wv.z + hv.w * wv.w;
        }
        s += __shfl_xor(s, 1); s += __shfl_xor(s, 2);
        s += __shfl_xor(s, 4); s += __shfl_xor(s, 8); s += __shfl_xor(s, 16);
        if (pj == 0) s0_lds[pm] = s;
    }

    // ---- preamble: h0 slice (this block's chunk) -> hbuf parity 0, WT ----
    {
        float v0 = hidden0[(size_t)bglob * H + kdim];
        unsigned int v16 = (unsigned int)bf16_rne(v0);
        unsigned int p1  = (unsigned int)__shfl_xor((int)v16, 1);
        unsigned int d   = (pj & 1) ? ((v16 << 16) | p1) : ((p1 << 16) | v16);
        const int base = lane & 56;
        unsigned int dw0 = (unsigned int)__shfl((int)d, base);
        unsigned int dw1 = (unsigned int)__shfl((int)d, base + 2);
        unsigned int dw2 = (unsigned int)__shfl((int)d, base + 4);
        unsigned int dw3 = (unsigned int)__shfl((int)d, base + 6);
        if ((pj & 7) == 0) {
            int4v v4 = { (int)dw0, (int)dw1, (int)dw2, (int)dw3 };
            store16_wt(hbuf + (size_t)(0 * GROUPS + g) * GRP_SHORTS + hoff, v4);
        }
    }
    __syncthreads();   // drains WT stores (vmcnt0 per wave)
    if (tid == 0)
        __hip_atomic_store(&flags[rb], 1u, __ATOMIC_RELAXED, __HIP_MEMORY_SCOPE_AGENT);
    if (wave == 0) {
        for (;;) {
            unsigned int v = __hip_atomic_load(&flags[lane & 31], __ATOMIC_RELAXED,
                                               __HIP_MEMORY_SCOPE_AGENT);
            if (__all((int)(v >= 1u))) break;
        }
        (void)__hip_atomic_load(&flags[lane & 31], __ATOMIC_ACQUIRE,
                                __HIP_MEMORY_SCOPE_AGENT);
    }
    __syncthreads();

    for (int t = 0; t < T; ++t) {
        // ---- phase A: DMA h_t (32 KB) -> LDS (4 chunks/wave); wave1: t-1 head ----
        const unsigned short* hsrc = hbuf + (size_t)((t & 1) * GROUPS + g) * GRP_SHORTS;
        #pragma unroll
        for (int i = 0; i < 4; ++i) {
            const int c = wave * 4 + i;
            dma16(hsrc + c * 512 + lane * 8, planes + c * 512);
        }
        if (wave == 1 && rb < MPG && t > 0) {
            // batch m = rb: sum 32 block-partials written at step t-1
            const float* pr = pbuf + (size_t)((((t - 1) & 1) * GROUPS + g) * MPG + rb) * BPG;
            float v = pr[lane & 31];
            v += __shfl_xor(v, 1); v += __shfl_xor(v, 2); v += __shfl_xor(v, 4);
            v += __shfl_xor(v, 8); v += __shfl_xor(v, 16);
            if (lane == 0) out[(size_t)(g * MPG + rb) * T + (t - 1)] = v + bl;
        }
        __syncthreads();   // per-wave vmcnt drain => DMA complete

        // ---- phase B: MFMA. wave (kh,nh): 4 n-tiles x 16 batches x K/4 ----
        floatx4 acc[4];
        #pragma unroll
        for (int ntl = 0; ntl < 4; ++ntl) acc[ntl] = (floatx4){0.f, 0.f, 0.f, 0.f};
        #pragma unroll
        for (int kt = 0; kt < 8; ++kt) {
            const int c = kh * 8 + kt;
            bf16x8 ah = *(const bf16x8*)(planes + c * 512 + lane * 8);
            #pragma unroll
            for (int ntl = 0; ntl < 4; ++ntl)
                acc[ntl] = __builtin_amdgcn_mfma_f32_16x16x32_bf16(ah, w_hi[ntl][kt], acc[ntl], 0, 0, 0);
        }
        #pragma unroll
        for (int ntl = 0; ntl < 4; ++ntl) {     // C/D: col=lane&15, row=q*4+r
            const int nt = nh * 4 + ntl;
            #pragma unroll
            for (int r = 0; r < 4; ++r)
                Dlds[kh][nt][q * 4 + r][l15] = acc[ntl][r];
        }
        __syncthreads();

        // ---- phase C: pointwise (thread (pm, pj)) + pack + WT stores ----
        {
            const int nt0 = pj >> 4, nn = pj & 15;
            float gv[4];
            #pragma unroll
            for (int gt = 0; gt < 4; ++gt) {
                const int nt = gt * 2 + nt0;
                gv[gt] = Dlds[0][nt][pm][nn] + Dlds[1][nt][pm][nn]
                       + Dlds[2][nt][pm][nn] + Dlds[3][nt][pm][nn];
            }
            if (t == 0) {
                float s0 = s0_lds[pm];
                #pragma unroll
                for (int gt = 0; gt < 4; ++gt) gv[gt] += bias0_p[gt] - wih0_p[gt] * s0;
            } else {
                #pragma unroll
                for (int gt = 0; gt < 4; ++gt) gv[gt] += bias_p[gt];
            }
            float ig  = sigmoidf_(gv[0]);
            float fg  = sigmoidf_(gv[1]);
            float gt_ = tanhf(gv[2]);
            float og  = sigmoidf_(gv[3]);
            cstate = fg * cstate + ig * gt_;
            float hnew = og * tanhf(cstate);

            // pack 8 lanes' bf16 into one 16 B WT store into chunk rb
            unsigned int v16 = (unsigned int)bf16_rne(hnew);
            unsigned int p1  = (unsigned int)__shfl_xor((int)v16, 1);
            unsigned int d   = (pj & 1) ? ((v16 << 16) | p1) : ((p1 << 16) | v16);
            const int base = lane & 56;
            unsigned int dw0 = (unsigned int)__shfl((int)d, base);
            unsigned int dw1 = (unsigned int)__shfl((int)d, base + 2);
            unsigned int dw2 = (unsigned int)__shfl((int)d, base + 4);
            unsigned int dw3 = (unsigned int)__shfl((int)d, base + 6);
            if ((pj & 7) == 0) {
                int4v v4 = { (int)dw0, (int)dw1, (int)dw2, (int)dw3 };
                store16_wt(hbuf + (size_t)(((t + 1) & 1) * GROUPS + g) * GRP_SHORTS + hoff, v4);
            }
            // out-head partial: reduce over this block's 32 dims
            float po = wlin_p * hnew;
            po += __shfl_xor(po, 1); po += __shfl_xor(po, 2);
            po += __shfl_xor(po, 4); po += __shfl_xor(po, 8); po += __shfl_xor(po, 16);
            if (pj == 0)
                store4_wt(pbuf + (size_t)(((t & 1) * GROUPS + g) * MPG + pm) * BPG + rb, po);
        }
        __syncthreads();   // per-wave vmcnt(0): all WT stores at L3 before arrive

        // ---- phase D: arrive (tid0 store) + wave0 packed-flag poll + acquire ----
        {
            const unsigned int gen = (unsigned int)(t + 2);
            if (tid == 0)
                __hip_atomic_store(&flags[rb], gen, __ATOMIC_RELAXED, __HIP_MEMORY_SCOPE_AGENT);
            if (wave == 0) {
                for (;;) {
                    unsigned int v = __hip_atomic_load(&flags[lane & 31], __ATOMIC_RELAXED,
                                                       __HIP_MEMORY_SCOPE_AGENT);
                    if (__all((int)(v >= gen))) break;
                }
                (void)__hip_atomic_load(&flags[lane & 31], __ATOMIC_ACQUIRE,
                                        __HIP_MEMORY_SCOPE_AGENT);  // buffer_inv
            }
            __syncthreads();   // release whole block into step t+1
        }
    }

    // ---- epilogue: output column t = T-1 ----
    if (wave == 1 && rb < MPG) {
        const float* pr = pbuf + (size_t)((((T - 1) & 1) * GROUPS + g) * MPG + rb) * BPG;
        float v = pr[lane & 31];
        v += __shfl_xor(v, 1); v += __shfl_xor(v, 2); v += __shfl_xor(v, 4);
        v += __shfl_xor(v, 8); v += __shfl_xor(v, 16);
        if (lane == 0) out[(size_t)(g * MPG + rb) * T + (T - 1)] = v + bl;
    }
}

extern "C" void kernel_launch(void* const* d_in, const int* in_sizes, int n_in,
                              void* d_out, int out_size, void* d_ws, size_t ws_size,
                              hipStream_t stream) {
    const float* hidden0 = (const float*)d_in[0];
    const float* cell0   = (const float*)d_in[1];
    const float* Wih     = (const float*)d_in[2];
    const float* Whh     = (const float*)d_in[3];
    const float* bih     = (const float*)d_in[4];
    const float* bhh     = (const float*)d_in[5];
    const float* Wlin    = (const float*)d_in[6];
    const float* blin    = (const float*)d_in[7];
    float* out = (float*)d_out;
    float* ws  = (float*)d_ws;

    // zero the barrier flags
    hipMemsetAsync(d_ws, 0, 4096, stream);

    void* args[] = { &hidden0, &cell0, &Wih, &Whh, &bih, &bhh, &Wlin, &blin,
                     &out, &ws };
    hipLaunchCooperativeKernel((const void*)decoder_kernel,
                               dim3(GROUPS * BPG), dim3(NTHR), args, 0, stream);
}

// Round 11
// 1423.908 us; speedup vs baseline: 3.1881x; 1.0347x over previous
//
#include <hip/hip_runtime.h>
#include <math.h>

#define H      1024
#define B      128
#define T      256
#define GROUPS 8        // 8 groups x 32 blocks = 256 blocks (1/CU)
#define BPG    32       // blocks per group; block owns 32 dims = 128 gate rows
#define NTHR   512
#define MPG    16       // batches per group
#define DPB    32       // dims per block
#define GRP_SHORTS (MPG * H)   // 16384 shorts = 32 KB per group per parity

#define AS1 __attribute__((address_space(1)))

typedef __attribute__((ext_vector_type(8))) short  bf16x8;
typedef __attribute__((ext_vector_type(4))) float  floatx4;
typedef __attribute__((ext_vector_type(4))) int    int4v;

static __device__ __forceinline__ unsigned short bf16_rne(float f) {
    unsigned int u = __float_as_uint(f);
    u += 0x7FFF + ((u >> 16) & 1);
    return (unsigned short)(u >> 16);
}
static __device__ __forceinline__ float sigmoidf_(float x) { return 1.0f / (1.0f + __expf(-x)); }

// write-through stores: land at the device coherence point, leave no dirty L2
// line behind => no buffer_wbl2 needed anywhere in the loop (R4's key win).
static __device__ __forceinline__ void store16_wt(void* p, int4v v) {
    asm volatile("global_store_dwordx4 %0, %1, off sc0 sc1" :: "v"(p), "v"(v) : "memory");
}
static __device__ __forceinline__ void store4_wt(void* p, float v) {
    asm volatile("global_store_dword %0, %1, off sc0 sc1" :: "v"(p), "v"(v) : "memory");
}
// coherence-point load (bypass L1+L2): h is always read fresh, independent of
// the acquire-inv. No waitcnt inside — fenced later with register-tied asm.
static __device__ __forceinline__ int4v load16_nc(const void* p) {
    int4v v;
    asm volatile("global_load_dwordx4 %0, %1, off sc0 sc1" : "=v"(v) : "v"(p) : "memory");
    return v;
}

// Persistent LSTM decoder. 8 groups x 32 blocks. Group g owns batches
// [16g,16g+16); block rb owns dims [32rb,32rb+32) => 128 gate rows (8 n-tiles).
// W' = W_hh + W_ih[:,0](x)W_lin, hi-bf16, in registers. Wave w owns K-eighth
// [128w,128w+128) (4 chunks) and ALL 8 n-tiles => h loads go straight
// global->VGPR (no LDS staging, no phase-A sync). h chunk (1 KB, this block's
// 32 dims) is written by wave0 alone after a pointwise->LDS stash, so the
// drain before the flag arrive is one wave's single store.
// Barrier: R7-proven packed-flag protocol (tid0 relaxed arrive, wave0 gather
// poll + one ACQUIRE load per step for the buffer_inv covering pbuf).
__global__ __launch_bounds__(NTHR, 2) void decoder_kernel(
    const float* __restrict__ hidden0, const float* __restrict__ cell0,
    const float* __restrict__ Wih,     const float* __restrict__ Whh,
    const float* __restrict__ bih,     const float* __restrict__ bhh,
    const float* __restrict__ Wlin,    const float* __restrict__ blin,
    float* __restrict__ out,           float* __restrict__ ws)
{
    __shared__ float Dlds[8][8][MPG][18];         // 73.7 KB: [kh8][ntile][m][n+pad]
    __shared__ float s0_lds[MPG];
    __shared__ float postage[MPG];
    __shared__ __align__(16) unsigned short hstage[512];   // 1 KB, chunk layout

    const int blk  = blockIdx.x;
    const int g    = blk >> 5;          // group 0..7
    const int rb   = blk & 31;          // block in group 0..31
    const int tid  = threadIdx.x;
    const int lane = tid & 63;
    const int wave = tid >> 6;          // 8 waves: wave = K-eighth
    const int l15  = lane & 15;
    const int q    = lane >> 4;

    // ws: flags 8 groups x 64 uints (256 B apart) | hbuf 512 KB | pbuf 32 KB
    unsigned int*   flags = (unsigned int*)ws + g * 64;            // 32 used
    unsigned short* hbuf  = (unsigned short*)((char*)ws + 4096);   // [2][G][GRP_SHORTS]
    float*          pbuf  = (float*)((char*)ws + 4096 + 2 * GROUPS * GRP_SHORTS * 2); // [2][G][MPG][BPG]

    // ---- W' hi-bf16 B-fragments in registers: 8 n-tiles x K/8 = 32 frags ----
    bf16x8 w_hi[8][4];
    #pragma unroll
    for (int ntl = 0; ntl < 8; ++ntl) {
        const int gate = ntl >> 1;
        const int row  = gate * H + rb * DPB + (ntl & 1) * 16 + l15;
        const float* wrow  = Whh + (size_t)row * H;
        const float  wih0r = Wih[row * 2];
        #pragma unroll
        for (int kt = 0; kt < 4; ++kt) {
            const int k0 = wave * 128 + kt * 32 + q * 8;
            #pragma unroll
            for (int j = 0; j < 8; ++j) {
                float w = wrow[k0 + j] + wih0r * Wlin[k0 + j];
                w_hi[ntl][kt][j] = (short)bf16_rne(w);
            }
        }
    }

    // ---- pointwise-thread constants: thread (pm, pj); lane = (pm&1)*32+pj ----
    const int pm    = tid >> 5;               // batch in group 0..15
    const int pj    = tid & 31;               // dim within block 0..31
    const int bglob = g * MPG + pm;
    const int kdim  = rb * DPB + pj;
    const float bl  = blin[0];
    float bias_p[4], bias0_p[4], wih0_p[4];
    #pragma unroll
    for (int gt = 0; gt < 4; ++gt) {
        int r2 = gt * H + kdim;
        float b0 = bih[r2] + bhh[r2];
        float w0 = Wih[r2 * 2];
        bias0_p[gt] = b0;
        wih0_p[gt]  = w0;
        bias_p[gt]  = b0 + Wih[r2 * 2 + 1] + w0 * bl;   // folded bias (t>=1)
    }
    float cstate = cell0[(size_t)bglob * H + kdim];
    const float wlin_p = Wlin[kdim];

    // ---- s0[m] = Wlin . h0[m]  (t=0 rank-1 correction) ----
    {
        const float* hp = hidden0 + (size_t)bglob * H + pj * 32;
        const float* wp = Wlin + pj * 32;
        float s = 0.f;
        #pragma unroll 4
        for (int kk = 0; kk < 32; kk += 4) {
            float4 hv = *(const float4*)(hp + kk);
            float4 wv = *(const float4*)(wp + kk);
            s += hv.x * wv.x + hv.y * wv.y + hv.z * wv.z + hv.w * wv.w;
        }
        s += __shfl_xor(s, 1); s += __shfl_xor(s, 2);
        s += __shfl_xor(s, 4); s += __shfl_xor(s, 8); s += __shfl_xor(s, 16);
        if (pj == 0) s0_lds[pm] = s;
    }

    // ---- preamble: h0 -> hstage (chunk layout) -> wave0 WT store; barrier ----
    {
        float v0 = hidden0[(size_t)bglob * H + kdim];
        hstage[(pj >> 3) * 128 + pm * 8 + (pj & 7)] = bf16_rne(v0);
    }
    __syncthreads();
    if (wave == 0) {
        int4v hv = *(const int4v*)(hstage + lane * 8);
        store16_wt(hbuf + (size_t)(0 * GROUPS + g) * GRP_SHORTS + rb * 512 + lane * 8, hv);
        asm volatile("s_waitcnt vmcnt(0)" ::: "memory");
        if (lane == 0)
            __hip_atomic_store(&flags[rb], 1u, __ATOMIC_RELAXED, __HIP_MEMORY_SCOPE_AGENT);
        for (;;) {
            unsigned int v = __hip_atomic_load(&flags[lane & 31], __ATOMIC_RELAXED,
                                               __HIP_MEMORY_SCOPE_AGENT);
            if (__all((int)(v >= 1u))) break;
        }
        (void)__hip_atomic_load(&flags[lane & 31], __ATOMIC_ACQUIRE,
                                __HIP_MEMORY_SCOPE_AGENT);
    }
    __syncthreads();

    for (int t = 0; t < T; ++t) {
        // ---- phase A: direct h_t loads (this wave's 4 chunks) -> VGPRs ----
        const char* hsrc = (const char*)(hbuf + (size_t)((t & 1) * GROUPS + g) * GRP_SHORTS)
                         + wave * 4096 + lane * 16;
        int4v a0 = load16_nc(hsrc);
        int4v a1 = load16_nc(hsrc + 1024);
        int4v a2 = load16_nc(hsrc + 2048);
        int4v a3 = load16_nc(hsrc + 3072);
        if (wave == 1 && rb < MPG && t > 0) {
            // batch m = rb: sum 32 block-partials written at step t-1
            const float* pr = pbuf + (size_t)((((t - 1) & 1) * GROUPS + g) * MPG + rb) * BPG;
            float v = pr[lane & 31];
            v += __shfl_xor(v, 1); v += __shfl_xor(v, 2); v += __shfl_xor(v, 4);
            v += __shfl_xor(v, 8); v += __shfl_xor(v, 16);
            if (lane == 0) out[(size_t)(g * MPG + rb) * T + (t - 1)] = v + bl;
        }
        // fence: ties the loaded regs so MFMA cannot be scheduled before drain
        asm volatile("s_waitcnt vmcnt(0)" : "+v"(a0), "+v"(a1), "+v"(a2), "+v"(a3));

        // ---- phase B: MFMA. wave w: 8 n-tiles x 16 batches x K/8 ----
        bf16x8 a[4];
        a[0] = __builtin_bit_cast(bf16x8, a0);
        a[1] = __builtin_bit_cast(bf16x8, a1);
        a[2] = __builtin_bit_cast(bf16x8, a2);
        a[3] = __builtin_bit_cast(bf16x8, a3);
        floatx4 acc[8];
        #pragma unroll
        for (int ntl = 0; ntl < 8; ++ntl) acc[ntl] = (floatx4){0.f, 0.f, 0.f, 0.f};
        #pragma unroll
        for (int kt = 0; kt < 4; ++kt) {
            #pragma unroll
            for (int ntl = 0; ntl < 8; ++ntl)
                acc[ntl] = __builtin_amdgcn_mfma_f32_16x16x32_bf16(a[kt], w_hi[ntl][kt], acc[ntl], 0, 0, 0);
        }
        #pragma unroll
        for (int ntl = 0; ntl < 8; ++ntl) {     // C/D: col=lane&15, row=q*4+r
            #pragma unroll
            for (int r = 0; r < 4; ++r)
                Dlds[wave][ntl][q * 4 + r][l15] = acc[ntl][r];
        }
        __syncthreads();

        // ---- phase C: pointwise (thread (pm, pj)) -> LDS stash ----
        {
            const int nt0 = pj >> 4, nn = pj & 15;
            float gv[4];
            #pragma unroll
            for (int gt = 0; gt < 4; ++gt) {
                const int nt = gt * 2 + nt0;
                float s = 0.f;
                #pragma unroll
                for (int kk = 0; kk < 8; ++kk)
                    s += Dlds[kk][nt][pm][nn];
                gv[gt] = s;
            }
            if (t == 0) {
                float s0 = s0_lds[pm];
                #pragma unroll
                for (int gt = 0; gt < 4; ++gt) gv[gt] += bias0_p[gt] - wih0_p[gt] * s0;
            } else {
                #pragma unroll
                for (int gt = 0; gt < 4; ++gt) gv[gt] += bias_p[gt];
            }
            float ig  = sigmoidf_(gv[0]);
            float fg  = sigmoidf_(gv[1]);
            float gt_ = tanhf(gv[2]);
            float og  = sigmoidf_(gv[3]);
            cstate = fg * cstate + ig * gt_;
            float hnew = og * tanhf(cstate);

            hstage[(pj >> 3) * 128 + pm * 8 + (pj & 7)] = bf16_rne(hnew);
            float po = wlin_p * hnew;
            po += __shfl_xor(po, 1); po += __shfl_xor(po, 2);
            po += __shfl_xor(po, 4); po += __shfl_xor(po, 8); po += __shfl_xor(po, 16);
            if (pj == 0) postage[pm] = po;
        }
        __syncthreads();

        // ---- phase D: wave0 store + drain + arrive + poll + acquire ----
        if (wave == 0) {
            const unsigned int gen = (unsigned int)(t + 2);
            int4v hv = *(const int4v*)(hstage + lane * 8);
            store16_wt(hbuf + (size_t)(((t + 1) & 1) * GROUPS + g) * GRP_SHORTS
                       + rb * 512 + lane * 8, hv);
            if (lane < MPG)
                store4_wt(pbuf + (size_t)(((t & 1) * GROUPS + g) * MPG + lane) * BPG + rb,
                          postage[lane]);
            asm volatile("s_waitcnt vmcnt(0)" ::: "memory");   // drain wave0's WT stores
            if (lane == 0)
                __hip_atomic_store(&flags[rb], gen, __ATOMIC_RELAXED, __HIP_MEMORY_SCOPE_AGENT);
            for (;;) {
                unsigned int v = __hip_atomic_load(&flags[lane & 31], __ATOMIC_RELAXED,
                                                   __HIP_MEMORY_SCOPE_AGENT);
                if (__all((int)(v >= gen))) break;
            }
            (void)__hip_atomic_load(&flags[lane & 31], __ATOMIC_ACQUIRE,
                                    __HIP_MEMORY_SCOPE_AGENT);  // buffer_inv (pbuf freshness)
        }
        __syncthreads();   // release whole block into step t+1
    }

    // ---- epilogue: output column t = T-1 ----
    if (wave == 1 && rb < MPG) {
        const float* pr = pbuf + (size_t)((((T - 1) & 1) * GROUPS + g) * MPG + rb) * BPG;
        float v = pr[lane & 31];
        v += __shfl_xor(v, 1); v += __shfl_xor(v, 2); v += __shfl_xor(v, 4);
        v += __shfl_xor(v, 8); v += __shfl_xor(v, 16);
        if (lane == 0) out[(size_t)(g * MPG + rb) * T + (T - 1)] = v + bl;
    }
}

extern "C" void kernel_launch(void* const* d_in, const int* in_sizes, int n_in,
                              void* d_out, int out_size, void* d_ws, size_t ws_size,
                              hipStream_t stream) {
    const float* hidden0 = (const float*)d_in[0];
    const float* cell0   = (const float*)d_in[1];
    const float* Wih     = (const float*)d_in[2];
    const float* Whh     = (const float*)d_in[3];
    const float* bih     = (const float*)d_in[4];
    const float* bhh     = (const float*)d_in[5];
    const float* Wlin    = (const float*)d_in[6];
    const float* blin    = (const float*)d_in[7];
    float* out = (float*)d_out;
    float* ws  = (float*)d_ws;

    // zero the barrier flags
    hipMemsetAsync(d_ws, 0, 4096, stream);

    void* args[] = { &hidden0, &cell0, &Wih, &Whh, &bih, &bhh, &Wlin, &blin,
                     &out, &ws };
    hipLaunchCooperativeKernel((const void*)decoder_kernel,
                               dim3(GROUPS * BPG), dim3(NTHR), args, 0, stream);
}